// Round 6
// baseline (2232.943 us; speedup 1.0000x reference)
//
#include <hip/hip_runtime.h>
#include <stdint.h>

#define B_    1024
#define TX_   512
#define TY_   32
#define NA_   64
#define NS_   128
#define VIN_  64
#define VOUT_ 32

typedef _Float16 v8h __attribute__((ext_vector_type(8)));  // 8 f16 (4 VGPRs)
typedef float v4f __attribute__((ext_vector_type(4)));     // 4 fp32 acc
typedef _Float16 h2 __attribute__((ext_vector_type(2)));   // packed f16 pair
typedef __fp16 fp16v2 __attribute__((ext_vector_type(2))); // builtin pkrtz return type

__device__ __forceinline__ float sigm(float x)   { return 1.0f / (1.0f + __expf(-x)); }
__device__ __forceinline__ float tanh_f(float x) { return 1.0f - 2.0f / (__expf(2.0f * x) + 1.0f); }

__device__ __forceinline__ uint32_t pkrtz(float a, float b) {
#if __has_builtin(__builtin_amdgcn_cvt_pkrtz)
  union { fp16v2 h; uint32_t u; } v; v.h = __builtin_amdgcn_cvt_pkrtz(a, b); return v.u;
#else
  union { h2 h; uint32_t u; } v; v.h[0] = (_Float16)a; v.h[1] = (_Float16)b; return v.u;
#endif
}
__device__ __forceinline__ float f16lo(uint32_t p) { union { uint32_t u; h2 h; } v; v.u = p; return (float)v.h[0]; }
__device__ __forceinline__ float f16hi(uint32_t p) { union { uint32_t u; h2 h; } v; v.u = p; return (float)v.h[1]; }
__device__ __forceinline__ float dot2(uint32_t w, uint32_t x, float acc) {
  union { uint32_t u; h2 h; } a, b; a.u = w; b.u = x;
#if __has_builtin(__builtin_amdgcn_fdot2)
  return __builtin_amdgcn_fdot2(a.h, b.h, acc, false);
#else
  return acc + (float)a.h[0] * (float)b.h[0] + (float)a.h[1] * (float)b.h[1];
#endif
}

// ---------------- prep: Wcat=[Wih_p|Whh_p] -> f16, swizzled so k_dec thread tid=(i*8+seg)
// holds 16 consecutive uint4s: wz[r][u] = uint4[tid*16 + r*4 + u] covering row j=r*128+i,
// k-range [(seg*4+u)*8, +8)
__global__ __launch_bounds__(256) void k_prep(const float* __restrict__ Wih_p,
                                              const float* __restrict__ Whh_p,
                                              unsigned short* __restrict__ Wsw) {
  int idx = blockIdx.x * 256 + threadIdx.x;   // < 512*256
  int j = idx >> 8, k = idx & 255;
  float w = (k < 128) ? Wih_p[j * 128 + k] : Whh_p[j * 128 + (k - 128)];
  int r = j >> 7, i = j & 127, kg = k >> 3, seg = kg >> 2, u = kg & 3, e = k & 7;
  union { _Float16 h; unsigned short s; } cv; cv.h = (_Float16)w;
  Wsw[(((i * 8 + seg) * 16 + r * 4 + u) << 3) + e] = cv.s;
}

// ---------------- encoder v2: 512 blocks = (256 batch-groups x 2 dirs), 4 batch each,
// f16 MFMA 16x16x32, weights in VGPR B-frags, pkrtz x-repack. 2 blocks/CU.
__global__ __launch_bounds__(256, 2) void k_enc(
    const float* __restrict__ X,
    const float* __restrict__ Wih_f, const float* __restrict__ Whh_f,
    const float* __restrict__ bih_f, const float* __restrict__ bhh_f,
    const float* __restrict__ Wih_b, const float* __restrict__ Whh_b,
    const float* __restrict__ bih_b, const float* __restrict__ bhh_b,
    unsigned short* __restrict__ pre16)
{
  const int tid = threadIdx.x, lane = tid & 63, wv = tid >> 6;
  const int dir = blockIdx.x & 1, b0 = (blockIdx.x >> 1) * 4;
  const int n = lane & 15, q = lane >> 4, hs = wv * 16;
  const float* Wih = dir ? Wih_b : Wih_f;
  const float* Whh = dir ? Whh_b : Whh_f;
  const float* bih = dir ? bih_b : bih_f;
  const float* bhh = dir ? bhh_b : bhh_f;

  __shared__ __align__(16) unsigned short hl[16 * 72];  // h f16 [m][k], 144B row stride

  v8h wx[4][2], wh[4][2];
  float bias[4];
#pragma unroll
  for (int g = 0; g < 4; ++g) {
    int row = g * 64 + hs + n;
    bias[g] = bih[row] + bhh[row];
#pragma unroll
    for (int kt = 0; kt < 2; ++kt) {
      const float* pi = Wih + row * 64 + kt * 32 + q * 8;
      const float* ph = Whh + row * 64 + kt * 32 + q * 8;
      v8h a, bb;
#pragma unroll
      for (int j = 0; j < 8; ++j) { a[j] = (_Float16)pi[j]; bb[j] = (_Float16)ph[j]; }
      wx[g][kt] = a; wh[g][kt] = bb;
    }
  }
  for (int i = tid; i < 16 * 36; i += 256) ((uint32_t*)hl)[i] = 0u;

  float c[4] = {0.f, 0.f, 0.f, 0.f};
  const float* xrow = X + (size_t)(b0 + (n & 3)) * (TX_ * VIN_) + q * 8;  // batch row (dup for n>=4)
  int t0 = dir ? (TX_ - 1) : 0;
  float4 pf0 = *(const float4*)(xrow + t0 * VIN_ + 0);
  float4 pf1 = *(const float4*)(xrow + t0 * VIN_ + 4);
  float4 pf2 = *(const float4*)(xrow + t0 * VIN_ + 32);
  float4 pf3 = *(const float4*)(xrow + t0 * VIN_ + 36);
  __syncthreads();

  for (int t = 0; t < TX_; ++t) {
    union { uint32_t u[4]; v8h h; } xa0, xa1;
    xa0.u[0] = pkrtz(pf0.x, pf0.y); xa0.u[1] = pkrtz(pf0.z, pf0.w);
    xa0.u[2] = pkrtz(pf1.x, pf1.y); xa0.u[3] = pkrtz(pf1.z, pf1.w);
    xa1.u[0] = pkrtz(pf2.x, pf2.y); xa1.u[1] = pkrtz(pf2.z, pf2.w);
    xa1.u[2] = pkrtz(pf3.x, pf3.y); xa1.u[3] = pkrtz(pf3.z, pf3.w);
    int tn = (t + 1 < TX_) ? t + 1 : t;
    int ti = dir ? (TX_ - 1 - tn) : tn;
    pf0 = *(const float4*)(xrow + ti * VIN_ + 0);
    pf1 = *(const float4*)(xrow + ti * VIN_ + 4);
    pf2 = *(const float4*)(xrow + ti * VIN_ + 32);
    pf3 = *(const float4*)(xrow + ti * VIN_ + 36);

    v8h ha0 = *(const v8h*)((const char*)hl + (lane & 15) * 144 + q * 16);
    v8h ha1 = *(const v8h*)((const char*)hl + (lane & 15) * 144 + 64 + q * 16);
    v4f acc[4];
#pragma unroll
    for (int g = 0; g < 4; ++g) {
      v4f a = {bias[g], bias[g], bias[g], bias[g]};
      a = __builtin_amdgcn_mfma_f32_16x16x32_f16(xa0.h, wx[g][0], a, 0, 0, 0);
      a = __builtin_amdgcn_mfma_f32_16x16x32_f16(xa1.h, wx[g][1], a, 0, 0, 0);
      a = __builtin_amdgcn_mfma_f32_16x16x32_f16(ha0, wh[g][0], a, 0, 0, 0);
      a = __builtin_amdgcn_mfma_f32_16x16x32_f16(ha1, wh[g][1], a, 0, 0, 0);
      acc[g] = a;
    }
    __syncthreads();   // all h reads done before overwrite
    int t_out = dir ? (TX_ - 1 - t) : t;
    if (q == 0) {      // valid batch rows m = r (0..3)
#pragma unroll
      for (int r = 0; r < 4; ++r) {
        float cc = sigm(acc[1][r]) * c[r] + sigm(acc[0][r]) * tanh_f(acc[2][r]);
        c[r] = cc;
        float h = sigm(acc[3][r]) * tanh_f(cc);
        union { _Float16 h; unsigned short s; } cv; cv.h = (_Float16)h;
        hl[r * 72 + hs + n] = cv.s;
        pre16[((size_t)(b0 + r) * TX_ + t_out) * NS_ + dir * 64 + hs + n] = cv.s;
      }
    }
    __syncthreads();
  }
}

// ---------------- decoder v4: 1024 blocks x 1024 thr, po LDS-resident (f16), weights in VGPRs,
// 5 barriers/step, no-max softmax, dot2 f16 math.
#define PO_   0        // 512 x 272 = 139264
#define EA_   139264   // 512 f32
#define RED_  141312   // 2048 f32 = 8192 (ctx partials; w1p overlay in prologue)
#define LGP_  149504   // 256 f32 (logits partials)
#define SL_   150528   // 128 f32
#define XPK_  151040   // 128 u32 f16-pairs: [ctx(64) | s(64)]
#define QV_   151552   // 16 f32
#define RR_   151616   // 16 f32
#define DSM_  151680

__global__ __launch_bounds__(1024, 4) void k_dec(
    const unsigned short* __restrict__ pre16,
    const unsigned short* __restrict__ Wsw,
    const float* __restrict__ W1, const float* __restrict__ b1,
    const float* __restrict__ W2, const float* __restrict__ b2,
    const float* __restrict__ W3, const float* __restrict__ b3,
    const float* __restrict__ bih_p, const float* __restrict__ bhh_p,
    float* __restrict__ Lg)
{
  extern __shared__ char smem[];
  char*     po  = smem + PO_;
  float*    ea  = (float*)(smem + EA_);
  float*    red = (float*)(smem + RED_);
  float*    lgp = (float*)(smem + LGP_);
  float*    sl  = (float*)(smem + SL_);
  uint32_t* xpk = (uint32_t*)(smem + XPK_);
  float*    qv  = (float*)(smem + QV_);
  float*    rr  = (float*)(smem + RR_);
  float*    w1p = (float*)(smem + RED_);    // prologue-only overlay

  const int tid = threadIdx.x, lane = tid & 63, wv = tid >> 6;
  const int b = blockIdx.x;
  const int zi_ = tid >> 3, seg = tid & 7;   // Z-phase: hidden idx, k-segment

  { // stage pre_out[b] (f16) -> LDS, 272B rows
    const uint4* src = (const uint4*)(pre16 + (size_t)b * (TX_ * NS_));
    for (int i = tid; i < TX_ * 16; i += 1024) {
      int t = i >> 4, d8 = i & 15;
      *(uint4*)(po + t * 272 + d8 * 16) = src[i];
    }
  }
  // decoder weights -> VGPRs: 16 consecutive uint4 per thread
  uint4 wz[4][4];
  {
    const uint4* wp = (const uint4*)(const void*)Wsw + (size_t)tid * 16;
#pragma unroll
    for (int r = 0; r < 4; ++r)
#pragma unroll
      for (int u = 0; u < 4; ++u) wz[r][u] = wp[r * 4 + u];
  }
  float bp[4];
#pragma unroll
  for (int r = 0; r < 4; ++r) bp[r] = bih_p[r * 128 + zi_] + bhh_p[r * 128 + zi_];
  float creg = 0.f;

  if (tid < 128) { sl[tid] = 0.f; xpk[tid] = 0u; }
  if (tid < 16)  qv[tid] = 0.f;
  for (int i = tid; i < 1280; i += 1024) w1p[i] = W1[(i >> 7) * 256 + 128 + (i & 127)];
  __syncthreads();

  // P[t] = pre_out[t] @ W1[:,128:].T + b1 -> f16 pairs in regs of threads 0..511
  uint32_t Pr[5] = {0u, 0u, 0u, 0u, 0u};
  if (tid < 512) {
    float a[10];
#pragma unroll
    for (int g = 0; g < 10; ++g) a[g] = b1[g];
    const uint4* prow = (const uint4*)(po + tid * 272);
    for (int i = 0; i < 32; ++i) {
      uint4 pk = prow[i];
      float v0 = f16lo(pk.x), v1 = f16hi(pk.x), v2 = f16lo(pk.y), v3 = f16hi(pk.y);
      float v4 = f16lo(pk.z), v5 = f16hi(pk.z), v6 = f16lo(pk.w), v7 = f16hi(pk.w);
#pragma unroll
      for (int g = 0; g < 10; ++g) {
        const float* wg = w1p + g * 128 + i * 8;
        a[g] += v0*wg[0] + v1*wg[1] + v2*wg[2] + v3*wg[3] + v4*wg[4] + v5*wg[5] + v6*wg[6] + v7*wg[7];
      }
    }
#pragma unroll
    for (int j = 0; j < 5; ++j) Pr[j] = pkrtz(a[2 * j], a[2 * j + 1]);
  }
  __syncthreads();   // w1p dead; red free

  for (int ty = 0; ty < TY_; ++ty) {
    // ---- Phase A: e_t + unnormalized exp + sum partials (waves 0-7); prev logits (wave 8)
    if (tid < 512) {
      float e = b2[0];
#pragma unroll
      for (int i = 0; i < 5; ++i) {
        uint32_t pr = Pr[i];
        e += W2[2 * i]     * tanh_f(f16lo(pr) + qv[2 * i]);
        e += W2[2 * i + 1] * tanh_f(f16hi(pr) + qv[2 * i + 1]);
      }
      e = fmaxf(e, 0.f);                 // e in [0, ~0.5] -> exp safe without max-sub
      float p = __expf(e);
      ea[tid] = p;
      float s = p;
#pragma unroll
      for (int off = 1; off < 64; off <<= 1) s += __shfl_xor(s, off);
      if (lane == 0) rr[wv] = s;
    } else if (tid < 544 && ty > 0) {
      int v = tid - 512;
      float a = b3[v];
#pragma unroll
      for (int i = 0; i < 8; ++i) a += lgp[v * 8 + i];
      Lg[(size_t)(ty - 1) * (B_ * VOUT_) + (size_t)b * VOUT_ + v] = a;
    }
    __syncthreads();                                   // (1)
    // ---- Phase C: context partials (16 waves)
    {
      int d8 = lane & 15, g4 = lane >> 4;
      const char* pbase = po + d8 * 16;
      float p8[8];
#pragma unroll
      for (int j = 0; j < 8; ++j) p8[j] = 0.f;
#pragma unroll
      for (int i = 0; i < 8; ++i) {
        int t = i * 64 + wv * 4 + g4;
        float al = ea[t];
        uint4 pk = *(const uint4*)(pbase + t * 272);
        p8[0] += al * f16lo(pk.x); p8[1] += al * f16hi(pk.x);
        p8[2] += al * f16lo(pk.y); p8[3] += al * f16hi(pk.y);
        p8[4] += al * f16lo(pk.z); p8[5] += al * f16hi(pk.z);
        p8[6] += al * f16lo(pk.w); p8[7] += al * f16hi(pk.w);
      }
#pragma unroll
      for (int off = 16; off < 64; off <<= 1) {
#pragma unroll
        for (int j = 0; j < 8; ++j) p8[j] += __shfl_xor(p8[j], off);
      }
      if (lane < 16) {
        float4* dst = (float4*)&red[wv * 128 + d8 * 8];
        dst[0] = make_float4(p8[0], p8[1], p8[2], p8[3]);
        dst[1] = make_float4(p8[4], p8[5], p8[6], p8[7]);
      }
    }
    __syncthreads();                                   // (2)
    if (tid < 64) {  // fold 16 partials, normalize by S, pack ctx f16
      float S = rr[0] + rr[1] + rr[2] + rr[3] + rr[4] + rr[5] + rr[6] + rr[7];
      float rs = 1.0f / S;
      float v0 = 0.f, v1 = 0.f;
#pragma unroll
      for (int w = 0; w < 16; ++w) {
        float2 rv = *(const float2*)&red[w * 128 + 2 * tid];
        v0 += rv.x; v1 += rv.y;
      }
      xpk[tid] = pkrtz(v0 * rs, v1 * rs);
    }
    __syncthreads();                                   // (3)
    // ---- Phase Z: z rows {i,128+i,256+i,384+i} x k-seg, reg weights; gates in seg==0
    {
      const uint4* xq = (const uint4*)(const void*)xpk + seg * 4;
      uint4 x0 = xq[0], x1 = xq[1], x2 = xq[2], x3 = xq[3];
      float z[4];
#pragma unroll
      for (int r = 0; r < 4; ++r) {
        float za = 0.f;
        za = dot2(wz[r][0].x, x0.x, za); za = dot2(wz[r][0].y, x0.y, za);
        za = dot2(wz[r][0].z, x0.z, za); za = dot2(wz[r][0].w, x0.w, za);
        za = dot2(wz[r][1].x, x1.x, za); za = dot2(wz[r][1].y, x1.y, za);
        za = dot2(wz[r][1].z, x1.z, za); za = dot2(wz[r][1].w, x1.w, za);
        za = dot2(wz[r][2].x, x2.x, za); za = dot2(wz[r][2].y, x2.y, za);
        za = dot2(wz[r][2].z, x2.z, za); za = dot2(wz[r][2].w, x2.w, za);
        za = dot2(wz[r][3].x, x3.x, za); za = dot2(wz[r][3].y, x3.y, za);
        za = dot2(wz[r][3].z, x3.z, za); za = dot2(wz[r][3].w, x3.w, za);
        z[r] = za;
      }
#pragma unroll
      for (int off = 1; off < 8; off <<= 1) {
#pragma unroll
        for (int r = 0; r < 4; ++r) z[r] += __shfl_xor(z[r], off);
      }
      if (seg == 0) {
        float cc = sigm(z[1] + bp[1]) * creg + sigm(z[0] + bp[0]) * tanh_f(z[2] + bp[2]);
        creg = cc;
        float s = sigm(z[3] + bp[3]) * tanh_f(cc);
        sl[zi_] = s;
        union { _Float16 h; unsigned short u; } cv; cv.h = (_Float16)s;
        ((unsigned short*)xpk)[128 + zi_] = cv.u;
      }
    }
    __syncthreads();                                   // (4)
    // ---- Phase G: q-next (wave 0) + logits partials (waves 4-7)
    if (wv == 0) {
      float s0 = sl[lane], s1 = sl[64 + lane];
      float p10[10];
#pragma unroll
      for (int g = 0; g < 10; ++g) p10[g] = s0 * W1[g * 256 + lane] + s1 * W1[g * 256 + 64 + lane];
#pragma unroll
      for (int off = 1; off < 64; off <<= 1) {
#pragma unroll
        for (int g = 0; g < 10; ++g) p10[g] += __shfl_xor(p10[g], off);
      }
      if (lane < 10) qv[lane] = p10[lane];
    } else if (wv >= 4 && wv < 8) {
      int r = tid - 256, v = r >> 3, kg = r & 7;
      float a = 0.f;
#pragma unroll
      for (int k = kg * 16; k < kg * 16 + 16; ++k) a += sl[k] * W3[v * 128 + k];
      lgp[v * 8 + kg] = a;
    }
    __syncthreads();                                   // (5)
  }
  if (tid < 32) {  // final step logits
    float a = b3[tid];
#pragma unroll
    for (int i = 0; i < 8; ++i) a += lgp[tid * 8 + i];
    Lg[(size_t)(TY_ - 1) * (B_ * VOUT_) + (size_t)b * VOUT_ + tid] = a;
  }
}

// ---------------- batch-softmax
__global__ __launch_bounds__(256) void k_red(const float* __restrict__ Lg, float2* __restrict__ MS) {
  int ty = blockIdx.x >> 5, v = blockIdx.x & 31;
  const float* src = Lg + (size_t)ty * (B_ * VOUT_) + v;
  int tid = threadIdx.x, lane = tid & 63, wv = tid >> 6;
  __shared__ float r8[8];
  float m = -3.4e38f;
  for (int bb = tid; bb < B_; bb += 256) m = fmaxf(m, src[(size_t)bb * VOUT_]);
#pragma unroll
  for (int off = 1; off < 64; off <<= 1) m = fmaxf(m, __shfl_xor(m, off));
  if (lane == 0) r8[wv] = m;
  __syncthreads();
  float mx = fmaxf(fmaxf(r8[0], r8[1]), fmaxf(r8[2], r8[3]));
  float s = 0.f;
  for (int bb = tid; bb < B_; bb += 256) s += __expf(src[(size_t)bb * VOUT_] - mx);
#pragma unroll
  for (int off = 1; off < 64; off <<= 1) s += __shfl_xor(s, off);
  __syncthreads();
  if (lane == 0) r8[4 + wv] = s;
  __syncthreads();
  if (tid == 0) MS[blockIdx.x] = make_float2(mx, r8[4] + r8[5] + r8[6] + r8[7]);
}

__global__ __launch_bounds__(256) void k_out(const float* __restrict__ Lg,
                                             const float2* __restrict__ MS,
                                             float* __restrict__ out) {
  int i = blockIdx.x * 256 + threadIdx.x;          // < 1048576, layout (ty,b,v)
  int ty = i >> 15, b = (i >> 5) & 1023, v = i & 31;
  float2 ms = MS[ty * 32 + v];
  out[(size_t)b * (TY_ * VOUT_) + ty * VOUT_ + v] = __expf(Lg[i] - ms.x) / ms.y;
}

// ---------------- ws layout (bytes): pre16 134217728 | Wsw 262144 | Lg 4194304 | MS 8192
#define WS_PRE 0
#define WS_WSW 134217728
#define WS_LG  134479872
#define WS_MS  138674176

extern "C" void kernel_launch(void* const* d_in, const int* in_sizes, int n_in,
                              void* d_out, int out_size, void* d_ws, size_t ws_size,
                              hipStream_t stream) {
  const float* X     = (const float*)d_in[0];
  const float* Wih_f = (const float*)d_in[1];
  const float* Whh_f = (const float*)d_in[2];
  const float* bih_f = (const float*)d_in[3];
  const float* bhh_f = (const float*)d_in[4];
  const float* Wih_b = (const float*)d_in[5];
  const float* Whh_b = (const float*)d_in[6];
  const float* bih_b = (const float*)d_in[7];
  const float* bhh_b = (const float*)d_in[8];
  const float* Wih_p = (const float*)d_in[9];
  const float* Whh_p = (const float*)d_in[10];
  const float* bih_p = (const float*)d_in[11];
  const float* bhh_p = (const float*)d_in[12];
  const float* W1    = (const float*)d_in[13];
  const float* b1    = (const float*)d_in[14];
  const float* W2    = (const float*)d_in[15];
  const float* b2    = (const float*)d_in[16];
  const float* W3    = (const float*)d_in[17];
  const float* b3    = (const float*)d_in[18];

  char* ws = (char*)d_ws;
  unsigned short* pre16 = (unsigned short*)(ws + WS_PRE);
  unsigned short* Wsw   = (unsigned short*)(ws + WS_WSW);
  float*          Lg    = (float*)(ws + WS_LG);
  float2*         MS    = (float2*)(ws + WS_MS);

  (void)hipFuncSetAttribute((const void*)k_dec, hipFuncAttributeMaxDynamicSharedMemorySize, DSM_);

  k_prep<<<512, 256, 0, stream>>>(Wih_p, Whh_p, Wsw);
  k_enc<<<512, 256, 0, stream>>>(X, Wih_f, Whh_f, bih_f, bhh_f,
                                 Wih_b, Whh_b, bih_b, bhh_b, pre16);
  k_dec<<<1024, 1024, DSM_, stream>>>(pre16, Wsw, W1, b1, W2, b2, W3, b3,
                                      bih_p, bhh_p, Lg);
  k_red<<<1024, 256, 0, stream>>>(Lg, MS);
  k_out<<<4096, 256, 0, stream>>>(Lg, MS, (float*)d_out);
}